// Round 1
// 225.699 us; speedup vs baseline: 1.1730x; 1.1730x over previous
//
#include <hip/hip_runtime.h>
#include <hip/hip_bf16.h>

#define Bn   8
#define Cn   64
#define Nn   40962
#define Kn   7
#define OUTn 64
// flattened K dim = Kn*Cn = 448 = 14 chunks of 32

typedef __bf16 bf16x8 __attribute__((ext_vector_type(8)));
typedef __bf16 bf16x4 __attribute__((ext_vector_type(4)));
typedef float  f32x4  __attribute__((ext_vector_type(4)));

// ---------------------------------------------------------------------------
// Convert W [64,448] f32 -> bf16 once per call.
// ---------------------------------------------------------------------------
__global__ __launch_bounds__(256) void convw_kernel(
    const float* __restrict__ W, __bf16* __restrict__ Wb)
{
    int i = blockIdx.x * 256 + threadIdx.x;
    if (i < OUTn * Kn * Cn) Wb[i] = (__bf16)W[i];
}

// ---------------------------------------------------------------------------
// Pass 1: transpose+convert x [B, C, N] f32 -> xT [nb, N, C] bf16.
// v2: 128-n tile. float2 global reads (8 B/lane, always 8B-aligned since
// Nn*4 % 8 == 0). f32->bf16 conversion BEFORE LDS: LDS holds u32 = packed
// bf16 pair (n even in low half). All LDS ops are b32, conflict-free
// (write: bank = lane&31 2-way; read: broadcast pairs). Output side emits
// fully-coalesced 1KB-per-wave-instruction bf16x8 stores.
// ---------------------------------------------------------------------------
__global__ __launch_bounds__(256) void transpose_kernel(
    const float* __restrict__ x, __bf16* __restrict__ xT, int b0)
{
    __shared__ unsigned int tile[64][65];   // [c][n-pair slot]; +1 pad
    const int tid  = threadIdx.x;
    const int lane = tid & 63;
    const int w    = tid >> 6;
    const int n0   = blockIdx.x * 128;
    const int bl   = blockIdx.y;            // local batch in chunk
    const int b    = b0 + bl;
    const size_t xb = (size_t)b * Cn * Nn;

    const int n = n0 + lane * 2;
    if (n < Nn) {
#pragma unroll
        for (int i = 0; i < 16; ++i) {
            const int c = w * 16 + i;
            const float2 v = *(const float2*)(x + xb + (size_t)c * Nn + n);
            const unsigned short ua =
                __builtin_bit_cast(unsigned short, (__bf16)v.x);
            const unsigned short ub =
                __builtin_bit_cast(unsigned short, (__bf16)v.y);
            tile[c][lane] = ((unsigned)ub << 16) | (unsigned)ua;
        }
    }
    __syncthreads();

    // Output: 4 iters; each wave-instr = 8 rows x 128 B = 1 KB contiguous.
    const int rsub = lane >> 3;   // 0..7: row within 8-row stripe
    const int cblk = lane & 7;    // 16-B chunk within the 128-B row
#pragma unroll
    for (int it = 0; it < 4; ++it) {
        const int row = it * 32 + w * 8 + rsub;
        const int n1  = n0 + row;
        if (n1 < Nn) {
            const int slot = row >> 1;
            const int sh   = (row & 1) * 16;
            bf16x8 frag;
#pragma unroll
            for (int e = 0; e < 8; ++e) {
                const unsigned u = tile[cblk * 8 + e][slot];
                frag[e] = __builtin_bit_cast(
                    __bf16, (unsigned short)((u >> sh) & 0xffffu));
            }
            *(bf16x8*)(xT + ((size_t)bl * Nn + n1) * Cn + cblk * 8) = frag;
        }
    }
}

// ---------------------------------------------------------------------------
// Pass 2 v2: gather-GEMM, MFMA 16x16x32 bf16.
// Block = 4 waves, 64 vertices. Wave w owns output strip o in [16w, 16w+16):
//   A (= W rows 16w..16w+16) lives ENTIRELY in registers (14 x bf16x8) --
//   removes the 294 MB A-side L2 stream and frees acc down to 16 VGPRs.
// B rows are gathered into LDS with global_load_lds(16B), double-buffered
// per kn (stage kn+1 while MFMAs consume kn). LDS rows are 128 B so all
// chunks alias one bank group; fixed by chunk-permuted SOURCE addresses
// (slot s of row r holds chunk s ^ (r&7)); LDS dest stays linear as the
// hardware requires. Reader applies the same XOR -> uniform 8 lanes/slot.
// bl = blockIdx.x % curB pins each batch to one XCD when curB == 8.
// ---------------------------------------------------------------------------
__global__ __launch_bounds__(256) void gconv_kernel(
    const __bf16* __restrict__ xT,    // [nb, N, C] bf16
    const int*    __restrict__ nbr,   // [N*7] int32
    const __bf16* __restrict__ Wb,    // [64, 448] bf16
    const float*  __restrict__ bias,  // [64] f32
    float*        __restrict__ out,   // [B, 64, N] f32
    int b0, int curB)
{
    __shared__ __bf16 buf[2][64][64];   // 2 x 8 KB: [parity][vertex row][c]

    const int bl    = blockIdx.x % curB;
    const int vtile = blockIdx.x / curB;
    const int w     = threadIdx.x >> 6;   // wave id == output strip
    const int l     = threadIdx.x & 63;
    const int col   = l & 15;
    const int quad  = l >> 4;
    const int b     = b0 + bl;
    const int v0    = vtile * 64;

    const __bf16* xb = xT + (size_t)bl * Nn * Cn;

    // ---- A fragments: W rows w*16+col, all 14 k-chunks, in registers ----
    bf16x8 aW[14];
#pragma unroll
    for (int kc = 0; kc < 14; ++kc)
        aW[kc] = *(const bf16x8*)(Wb + (size_t)(w * 16 + col) * (Kn * Cn)
                                     + kc * 32 + quad * 8);

    // ---- neighbor byte-offsets for the rows this lane stages ----
    // staging row r = w*16 + j*8 + (l>>3); r&7 == l>>3
    const int rme = l >> 3;
    int ofs[2][7];
#pragma unroll
    for (int j = 0; j < 2; ++j) {
        int v = v0 + w * 16 + j * 8 + rme;
        if (v > Nn - 1) v = Nn - 1;
#pragma unroll
        for (int kn = 0; kn < 7; ++kn) {
            int id = nbr[v * 7 + kn];
            id = id < 0 ? 0 : (id >= Nn ? Nn - 1 : id);
            ofs[j][kn] = id * (Cn * 2);          // byte offset of 128-B row
        }
    }
    // chunk-permuted source offset: LDS slot (l&7) receives chunk (l&7)^rme
    const int srcoff = ((l & 7) ^ rme) * 16;

#define STAGE(p_, kn_)                                                        \
    {                                                                         \
        _Pragma("unroll")                                                     \
        for (int j = 0; j < 2; ++j) {                                         \
            const char* src_ = (const char*)xb + ofs[j][kn_] + srcoff;        \
            __builtin_amdgcn_global_load_lds(                                 \
                (const unsigned int*)src_,                                    \
                (unsigned int*)&buf[p_][w * 16 + j * 8][0], 16, 0, 0);        \
        }                                                                     \
    }

    f32x4 acc[4];
#pragma unroll
    for (int t = 0; t < 4; ++t)
        acc[t] = (f32x4){0.f, 0.f, 0.f, 0.f};

    STAGE(0, 0)
    __syncthreads();

#pragma unroll
    for (int kn = 0; kn < 7; ++kn) {
        if (kn < 6) STAGE((kn + 1) & 1, kn + 1)
        const int p = kn & 1;
#pragma unroll
        for (int h = 0; h < 2; ++h) {          // kc = kn*2 + h
            const int kc = kn * 2 + h;
            const int q  = h * 4 + quad;       // logical 16-B chunk 0..7
#pragma unroll
            for (int t = 0; t < 4; ++t) {
                const int r    = t * 16 + col;
                const int slot = q ^ (r & 7);
                const bf16x8 bf = *(const bf16x8*)&buf[p][r][slot * 8];
                acc[t] = __builtin_amdgcn_mfma_f32_16x16x32_bf16(
                    aW[kc], bf, acc[t], 0, 0, 0);
            }
        }
        __syncthreads();   // drains vmcnt(0): staged kn+1 ready, reads done
    }
#undef STAGE

    // ---- epilogue: C/D col = lane&15 -> vertex, row = quad*4+r -> o ----
#pragma unroll
    for (int r4 = 0; r4 < 4; ++r4) {
        const int o  = w * 16 + quad * 4 + r4;
        const float bv = bias[o];
#pragma unroll
        for (int t = 0; t < 4; ++t) {
            const int n = v0 + t * 16 + col;
            if (n < Nn)
                out[((size_t)b * OUTn + o) * Nn + n] = acc[t][r4] + bv;
        }
    }
}

// ---------------------------------------------------------------------------
// Fallback: no workspace needed. Pure f32. Slow but correct.
// ---------------------------------------------------------------------------
__global__ __launch_bounds__(256) void naive_kernel(
    const float* __restrict__ x,      // [B, C, N]
    const int*   __restrict__ nbr,
    const float* __restrict__ W,
    const float* __restrict__ bias,
    float*       __restrict__ out)
{
    __shared__ float xs[4][Kn * Cn];
    const int v = threadIdx.x >> 6;
    const int o = threadIdx.x & 63;
    const int b = blockIdx.y;
    const int n = blockIdx.x * 4 + v;
    const bool ok = n < Nn;
    const int nn = ok ? n : 0;

#pragma unroll
    for (int k = 0; k < Kn; ++k) {
        int id = nbr[nn * Kn + k];
        id = id < 0 ? 0 : (id >= Nn ? Nn - 1 : id);
        xs[v][k * Cn + o] = x[((size_t)b * Cn + o) * Nn + id];
    }
    __syncthreads();

    float acc = bias[o];
    for (int j = 0; j < Kn * Cn; ++j)
        acc += W[o * (Kn * Cn) + j] * xs[v][j];

    if (ok)
        out[((size_t)b * OUTn + o) * Nn + n] = acc;
}

extern "C" void kernel_launch(void* const* d_in, const int* in_sizes, int n_in,
                              void* d_out, int out_size, void* d_ws, size_t ws_size,
                              hipStream_t stream)
{
    const float* x    = (const float*)d_in[0];
    const int*   nbr  = (const int*)d_in[1];
    const float* W    = (const float*)d_in[2];
    const float* bias = (const float*)d_in[3];
    float*       out  = (float*)d_out;

    const size_t w_bytes     = (size_t)OUTn * Kn * Cn * sizeof(__bf16); // 57344
    const size_t batch_bytes = (size_t)Nn * Cn * sizeof(__bf16);        // 5.24 MB
    int nb = 0;
    if (ws_size > w_bytes)
        nb = (int)((ws_size - w_bytes) / batch_bytes);
    if (nb > Bn) nb = Bn;

    if (nb >= 1) {
        __bf16* Wb = (__bf16*)d_ws;
        __bf16* xT = (__bf16*)((char*)d_ws + w_bytes);

        convw_kernel<<<(OUTn * Kn * Cn + 255) / 256, 256, 0, stream>>>(W, Wb);

        const int vtiles = (Nn + 63) / 64;     // 641
        for (int b0 = 0; b0 < Bn; b0 += nb) {
            int cur = (Bn - b0) < nb ? (Bn - b0) : nb;
            dim3 tgrid((Nn + 127) / 128, cur);
            transpose_kernel<<<tgrid, 256, 0, stream>>>(x, xT, b0);
            gconv_kernel<<<vtiles * cur, 256, 0, stream>>>(xT, nbr, Wb, bias, out, b0, cur);
        }
    } else {
        dim3 ngrid((Nn + 3) / 4, Bn);
        naive_kernel<<<ngrid, 256, 0, stream>>>(x, nbr, W, bias, out);
    }
}

// Round 2
// 221.772 us; speedup vs baseline: 1.1937x; 1.0177x over previous
//
#include <hip/hip_runtime.h>
#include <hip/hip_bf16.h>

#define Bn   8
#define Cn   64
#define Nn   40962
#define Kn   7
#define OUTn 64
// flattened K dim = Kn*Cn = 448 = 14 chunks of 32

typedef __bf16 bf16x8 __attribute__((ext_vector_type(8)));
typedef __bf16 bf16x4 __attribute__((ext_vector_type(4)));
typedef float  f32x4  __attribute__((ext_vector_type(4)));

// ---------------------------------------------------------------------------
// Pass 1: transpose+convert x [B, C, N] f32 -> xT [nb, N, C] bf16.
// 128-n tile; float2 global reads; f32->bf16 packed to u32 BEFORE LDS so all
// LDS traffic is b32 and ~conflict-free; output side emits coalesced
// 1KB-per-wave-instruction bf16x8 stores. convw (W f32->bf16, 28672 elems)
// is folded into the first 112 blocks of the bl==0 slice.
// ---------------------------------------------------------------------------
__global__ __launch_bounds__(256) void transpose_kernel(
    const float* __restrict__ x, __bf16* __restrict__ xT,
    const float* __restrict__ W, __bf16* __restrict__ Wb, int b0)
{
    __shared__ unsigned int tile[64][65];   // [c][n-pair slot]; +1 pad
    const int tid  = threadIdx.x;
    const int lane = tid & 63;
    const int w    = tid >> 6;
    const int n0   = blockIdx.x * 128;
    const int bl   = blockIdx.y;            // local batch in chunk
    const int b    = b0 + bl;
    const size_t xb = (size_t)b * Cn * Nn;

    // fused convw: 112 blocks x 256 threads = 28672 elements (idempotent)
    if (bl == 0) {
        const int wi = blockIdx.x * 256 + tid;
        if (wi < OUTn * Kn * Cn) Wb[wi] = (__bf16)W[wi];
    }

    const int n = n0 + lane * 2;
    if (n < Nn) {
#pragma unroll
        for (int i = 0; i < 16; ++i) {
            const int c = w * 16 + i;
            const float2 v = *(const float2*)(x + xb + (size_t)c * Nn + n);
            const unsigned short ua =
                __builtin_bit_cast(unsigned short, (__bf16)v.x);
            const unsigned short ub =
                __builtin_bit_cast(unsigned short, (__bf16)v.y);
            tile[c][lane] = ((unsigned)ub << 16) | (unsigned)ua;
        }
    }
    __syncthreads();

    // Output: 4 iters; each wave-instr = 8 rows x 128 B = 1 KB contiguous.
    const int rsub = lane >> 3;   // 0..7: row within 8-row stripe
    const int cblk = lane & 7;    // 16-B chunk within the 128-B row
#pragma unroll
    for (int it = 0; it < 4; ++it) {
        const int row = it * 32 + w * 8 + rsub;
        const int n1  = n0 + row;
        if (n1 < Nn) {
            const int slot = row >> 1;
            const int sh   = (row & 1) * 16;
            bf16x8 frag;
#pragma unroll
            for (int e = 0; e < 8; ++e) {
                const unsigned u = tile[cblk * 8 + e][slot];
                frag[e] = __builtin_bit_cast(
                    __bf16, (unsigned short)((u >> sh) & 0xffffu));
            }
            *(bf16x8*)(xT + ((size_t)bl * Nn + n1) * Cn + cblk * 8) = frag;
        }
    }
}

// ---------------------------------------------------------------------------
// Pass 2 v3: gather-GEMM, MFMA 16x16x32 bf16, T3+T4 deep pipeline.
// Block = 4 waves, 64 vertices. Wave w owns output strip o in [16w,16w+16):
// A (W rows) entirely in registers. B rows gathered into LDS with
// global_load_lds(16B), NBUF=4 ring, depth-3 prefetch, counted
// s_waitcnt vmcnt(N) (4,4,4,4,4,2,0 taper) + raw s_barrier -- gather
// latency for stage kn is hidden under 3 stages of MFMA work instead of
// being drained by __syncthreads' vmcnt(0) every stage.
// Safety: each wave waits its OWN vmcnt before s_barrier => after barrier
// all waves' stage-kn rows are in LDS. Buffer (kn+3)&3 overwritten in iter
// kn was last ds_read in iter kn-1; any wave past the iter-kn barrier has
// issued its iter-(kn-1) MFMAs (hw lgkm wait precedes them) => reads
// retired. sched_barrier(0) pins ds_reads below the barrier (rule #18).
// Chunk-permuted SOURCE addresses keep LDS linear (global_load_lds
// requirement) while making ds_read_b128 conflict-free (slot s of row r
// holds chunk s ^ (r&7)). bl = blockIdx.x % curB pins batch -> XCD.
// ---------------------------------------------------------------------------
__global__ __launch_bounds__(256) void gconv_kernel(
    const __bf16* __restrict__ xT,    // [nb, N, C] bf16
    const int*    __restrict__ nbr,   // [N*7] int32
    const __bf16* __restrict__ Wb,    // [64, 448] bf16
    const float*  __restrict__ bias,  // [64] f32
    float*        __restrict__ out,   // [B, 64, N] f32
    int b0, int curB)
{
    __shared__ __bf16 buf[4][64][64];   // 4 x 8 KB ring: [stage&3][row][c]

    const int bl    = blockIdx.x % curB;
    const int vtile = blockIdx.x / curB;
    const int w     = threadIdx.x >> 6;   // wave id == output strip
    const int l     = threadIdx.x & 63;
    const int col   = l & 15;
    const int quad  = l >> 4;
    const int b     = b0 + bl;
    const int v0    = vtile * 64;

    const __bf16* xb = xT + (size_t)bl * Nn * Cn;

    // ---- A fragments: W rows w*16+col, all 14 k-chunks, in registers ----
    bf16x8 aW[14];
#pragma unroll
    for (int kc = 0; kc < 14; ++kc)
        aW[kc] = *(const bf16x8*)(Wb + (size_t)(w * 16 + col) * (Kn * Cn)
                                     + kc * 32 + quad * 8);

    // ---- neighbor byte-offsets for the rows this lane stages ----
    // staging row r = w*16 + j*8 + (l>>3); r&7 == l>>3
    const int rme = l >> 3;
    int ofs[2][7];
#pragma unroll
    for (int j = 0; j < 2; ++j) {
        int v = v0 + w * 16 + j * 8 + rme;
        if (v > Nn - 1) v = Nn - 1;
#pragma unroll
        for (int kn = 0; kn < 7; ++kn) {
            int id = nbr[v * 7 + kn];
            id = id < 0 ? 0 : (id >= Nn ? Nn - 1 : id);
            ofs[j][kn] = id * (Cn * 2);          // byte offset of 128-B row
        }
    }
    // chunk-permuted source offset: LDS slot (l&7) receives chunk (l&7)^rme
    const int srcoff = ((l & 7) ^ rme) * 16;

#define STAGE(p_, kn_)                                                        \
    {                                                                         \
        _Pragma("unroll")                                                     \
        for (int j = 0; j < 2; ++j) {                                         \
            const char* src_ = (const char*)xb + ofs[j][kn_] + srcoff;        \
            __builtin_amdgcn_global_load_lds(                                 \
                (const unsigned int*)src_,                                    \
                (unsigned int*)&buf[p_][w * 16 + j * 8][0], 16, 0, 0);        \
        }                                                                     \
    }

#define WAITVM_(n_) asm volatile("s_waitcnt vmcnt(" #n_ ")" ::: "memory")
#define WAITVM(n_) WAITVM_(n_)

    f32x4 acc[4];
#pragma unroll
    for (int t = 0; t < 4; ++t)
        acc[t] = (f32x4){0.f, 0.f, 0.f, 0.f};

    // prologue: prefetch stages 0,1,2 (6 loads/wave outstanding)
    STAGE(0, 0)
    STAGE(1, 1)
    STAGE(2, 2)

#define KNSTEP(kn_, vm_)                                                      \
    {                                                                         \
        WAITVM(vm_);                          /* own stage-kn loads done */   \
        __builtin_amdgcn_s_barrier();         /* => all waves' stage kn  */   \
        __builtin_amdgcn_sched_barrier(0);                                    \
        if ((kn_) + 3 < 7) STAGE(((kn_) + 3) & 3, (kn_) + 3)                  \
        __builtin_amdgcn_s_setprio(1);                                        \
        _Pragma("unroll")                                                     \
        for (int h = 0; h < 2; ++h) {         /* kc = kn*2 + h */             \
            const int q = h * 4 + quad;       /* logical 16-B chunk 0..7 */   \
            _Pragma("unroll")                                                 \
            for (int t = 0; t < 4; ++t) {                                     \
                const int r    = t * 16 + col;                                \
                const int slot = q ^ (r & 7);                                 \
                const bf16x8 bf =                                             \
                    *(const bf16x8*)&buf[(kn_) & 3][r][slot * 8];             \
                acc[t] = __builtin_amdgcn_mfma_f32_16x16x32_bf16(             \
                    aW[(kn_)*2 + h], bf, acc[t], 0, 0, 0);                    \
            }                                                                 \
        }                                                                     \
        __builtin_amdgcn_s_setprio(0);                                        \
    }

    KNSTEP(0, 4)
    KNSTEP(1, 4)
    KNSTEP(2, 4)
    KNSTEP(3, 4)
    KNSTEP(4, 4)
    KNSTEP(5, 2)
    KNSTEP(6, 0)

#undef KNSTEP
#undef STAGE

    // ---- epilogue: C/D col = lane&15 -> vertex, row = quad*4+r -> o ----
#pragma unroll
    for (int r4 = 0; r4 < 4; ++r4) {
        const int o  = w * 16 + quad * 4 + r4;
        const float bv = bias[o];
#pragma unroll
        for (int t = 0; t < 4; ++t) {
            const int n = v0 + t * 16 + col;
            if (n < Nn)
                out[((size_t)b * OUTn + o) * Nn + n] = acc[t][r4] + bv;
        }
    }
}

// ---------------------------------------------------------------------------
// Fallback: no workspace needed. Pure f32. Slow but correct.
// ---------------------------------------------------------------------------
__global__ __launch_bounds__(256) void naive_kernel(
    const float* __restrict__ x,      // [B, C, N]
    const int*   __restrict__ nbr,
    const float* __restrict__ W,
    const float* __restrict__ bias,
    float*       __restrict__ out)
{
    __shared__ float xs[4][Kn * Cn];
    const int v = threadIdx.x >> 6;
    const int o = threadIdx.x & 63;
    const int b = blockIdx.y;
    const int n = blockIdx.x * 4 + v;
    const bool ok = n < Nn;
    const int nn = ok ? n : 0;

#pragma unroll
    for (int k = 0; k < Kn; ++k) {
        int id = nbr[nn * Kn + k];
        id = id < 0 ? 0 : (id >= Nn ? Nn - 1 : id);
        xs[v][k * Cn + o] = x[((size_t)b * Cn + o) * Nn + id];
    }
    __syncthreads();

    float acc = bias[o];
    for (int j = 0; j < Kn * Cn; ++j)
        acc += W[o * (Kn * Cn) + j] * xs[v][j];

    if (ok)
        out[((size_t)b * OUTn + o) * Nn + n] = acc;
}

extern "C" void kernel_launch(void* const* d_in, const int* in_sizes, int n_in,
                              void* d_out, int out_size, void* d_ws, size_t ws_size,
                              hipStream_t stream)
{
    const float* x    = (const float*)d_in[0];
    const int*   nbr  = (const int*)d_in[1];
    const float* W    = (const float*)d_in[2];
    const float* bias = (const float*)d_in[3];
    float*       out  = (float*)d_out;

    const size_t w_bytes     = (size_t)OUTn * Kn * Cn * sizeof(__bf16); // 57344
    const size_t batch_bytes = (size_t)Nn * Cn * sizeof(__bf16);        // 5.24 MB
    int nb = 0;
    if (ws_size > w_bytes)
        nb = (int)((ws_size - w_bytes) / batch_bytes);
    if (nb > Bn) nb = Bn;

    if (nb >= 1) {
        __bf16* Wb = (__bf16*)d_ws;
        __bf16* xT = (__bf16*)((char*)d_ws + w_bytes);

        const int vtiles = (Nn + 63) / 64;     // 641
        for (int b0 = 0; b0 < Bn; b0 += nb) {
            int cur = (Bn - b0) < nb ? (Bn - b0) : nb;
            dim3 tgrid((Nn + 127) / 128, cur);
            transpose_kernel<<<tgrid, 256, 0, stream>>>(x, xT, W, Wb, b0);
            gconv_kernel<<<vtiles * cur, 256, 0, stream>>>(xT, nbr, Wb, bias, out, b0, cur);
        }
    } else {
        dim3 ngrid((Nn + 3) / 4, Bn);
        naive_kernel<<<ngrid, 256, 0, stream>>>(x, nbr, W, bias, out);
    }
}

// Round 4
// 205.914 us; speedup vs baseline: 1.2857x; 1.0770x over previous
//
#include <hip/hip_runtime.h>
#include <hip/hip_bf16.h>

#define Bn   8
#define Cn   64
#define Nn   40962
#define Kn   7
#define OUTn 64
#define NVT  641      // 64-vertex tiles per batch
// flattened K dim = Kn*Cn = 448 = 14 chunks of 32

typedef __bf16 bf16x8 __attribute__((ext_vector_type(8)));
typedef __bf16 bf16x4 __attribute__((ext_vector_type(4)));
typedef float  f32x4  __attribute__((ext_vector_type(4)));

// ---------------------------------------------------------------------------
// Pass 1: transpose+convert x [B, C, N] f32 -> xT [B, N, C] bf16.
// (unchanged from round 2 -- held constant as the control)
// ---------------------------------------------------------------------------
__global__ __launch_bounds__(256) void transpose_kernel(
    const float* __restrict__ x, __bf16* __restrict__ xT,
    const float* __restrict__ W, __bf16* __restrict__ Wb, int b0)
{
    __shared__ unsigned int tile[64][65];   // [c][n-pair slot]; +1 pad
    const int tid  = threadIdx.x;
    const int lane = tid & 63;
    const int w    = tid >> 6;
    const int n0   = blockIdx.x * 128;
    const int bl   = blockIdx.y;
    const int b    = b0 + bl;
    const size_t xb = (size_t)b * Cn * Nn;

    // fused convw: first 112 blocks of bl==0 slice cover 28672 W elements
    if (bl == 0) {
        const int wi = blockIdx.x * 256 + tid;
        if (wi < OUTn * Kn * Cn) Wb[wi] = (__bf16)W[wi];
    }

    const int n = n0 + lane * 2;
    if (n < Nn) {
#pragma unroll
        for (int i = 0; i < 16; ++i) {
            const int c = w * 16 + i;
            const float2 v = *(const float2*)(x + xb + (size_t)c * Nn + n);
            const unsigned short ua =
                __builtin_bit_cast(unsigned short, (__bf16)v.x);
            const unsigned short ub =
                __builtin_bit_cast(unsigned short, (__bf16)v.y);
            tile[c][lane] = ((unsigned)ub << 16) | (unsigned)ua;
        }
    }
    __syncthreads();

    const int rsub = lane >> 3;
    const int cblk = lane & 7;
#pragma unroll
    for (int it = 0; it < 4; ++it) {
        const int row = it * 32 + w * 8 + rsub;
        const int n1  = n0 + row;
        if (n1 < Nn) {
            const int slot = row >> 1;
            const int sh   = (row & 1) * 16;
            bf16x8 frag;
#pragma unroll
            for (int e = 0; e < 8; ++e) {
                const unsigned u = tile[cblk * 8 + e][slot];
                frag[e] = __builtin_bit_cast(
                    __bf16, (unsigned short)((u >> sh) & 0xffffu));
            }
            *(bf16x8*)(xT + ((size_t)bl * Nn + n1) * Cn + cblk * 8) = frag;
        }
    }
}

// ---------------------------------------------------------------------------
// Pass 2 v5: persistent-block gather-GEMM, full-tile staging, 2 barriers/tile.
// Evidence: depth-1 (80.7us) vs depth-3+counted-vmcnt (77.3us) were both null
// => the 8-barrier-per-tile convoy structure is the invariant cost, not
// prefetch depth. This version removes per-stage barriers entirely:
//   - 512 persistent blocks (2/CU, 57 KB LDS each); blk&7 = batch = XCD.
//   - aW loaded ONCE per persistent block: A-refetch 287 MB -> 29 MB
//     (rounds 1-3 silently re-streamed all of W per 64-vertex block).
//   - per tile: all 7 kn-stages staged fire-and-forget (14 global_load_lds
//     per wave in flight, vs 2 before), next tile's neighbor indices
//     prefetched under the same latency, ONE __syncthreads, then
//     56 ds_read_b128 + 56 MFMA per wave with no further waits.
//   - stage latency of one block hides under the co-resident block's
//     compute phase (statistical phase interleave at 2 blocks/CU).
// LDS XOR scheme unchanged (slot s of row r holds chunk s^(r&7), applied on
// the per-lane global SOURCE address; LDS dest stays linear as
// global_load_lds requires; reader XORs the slot) -- proven conflict-free
// (SQ_LDS_BANK_CONFLICT == 0 in rounds 1-2).
// ---------------------------------------------------------------------------
__global__ __launch_bounds__(256, 2) void gconv_kernel(
    const __bf16* __restrict__ xT,    // [B, N, C] bf16
    const int*    __restrict__ nbr,   // [N*7] int32
    const __bf16* __restrict__ Wb,    // [64, 448] bf16
    const float*  __restrict__ bias,  // [64] f32
    float*        __restrict__ out)   // [B, 64, N] f32
{
    __shared__ __bf16 sbuf[Kn][64][64];   // 57344 B: [kn][vertex row][c]

    const int blk  = blockIdx.x;
    const int bl   = blk & 7;         // batch == XCD
    const int grp  = blk >> 3;        // 0..63 within batch
    const int w    = threadIdx.x >> 6;
    const int l    = threadIdx.x & 63;
    const int col  = l & 15;
    const int quad = l >> 4;
    const int rme  = l >> 3;
    const int srcoff = ((l & 7) ^ rme) * 16;
    const __bf16* xb = xT + (size_t)bl * Nn * Cn;

    // ---- A fragments: W rows w*16+col, all 14 k-chunks, ONCE per block ----
    bf16x8 aW[14];
#pragma unroll
    for (int kc = 0; kc < 14; ++kc)
        aW[kc] = *(const bf16x8*)(Wb + (size_t)(w * 16 + col) * (Kn * Cn)
                                     + kc * 32 + quad * 8);

    const float bv[4] = {bias[w * 16 + quad * 4 + 0],
                         bias[w * 16 + quad * 4 + 1],
                         bias[w * 16 + quad * 4 + 2],
                         bias[w * 16 + quad * 4 + 3]};

    // neighbor byte-offsets for the rows this lane stages (rows w*16+j*8+rme)
#define LOADIDX(vt_, dst_)                                                    \
    {                                                                         \
        _Pragma("unroll")                                                     \
        for (int j = 0; j < 2; ++j) {                                         \
            int v = (vt_)*64 + w * 16 + j * 8 + rme;                          \
            if (v > Nn - 1) v = Nn - 1;                                       \
            _Pragma("unroll")                                                 \
            for (int kn = 0; kn < Kn; ++kn) {                                 \
                int id = nbr[v * 7 + kn];                                     \
                id = id < 0 ? 0 : (id >= Nn ? Nn - 1 : id);                   \
                dst_[j][kn] = id * (Cn * 2);                                  \
            }                                                                 \
        }                                                                     \
    }

    int ofsA[2][Kn];
    LOADIDX(grp, ofsA)

    for (int vt = grp; vt < NVT; vt += 64) {
        __syncthreads();   // WAR: prev tile's laggard ds_reads done before restage

        // ---- stage ALL 7 kn (14 fire-and-forget global_load_lds / wave) ----
#pragma unroll
        for (int kn = 0; kn < Kn; ++kn) {
#pragma unroll
            for (int j = 0; j < 2; ++j) {
                const char* src_ = (const char*)xb + ofsA[j][kn] + srcoff;
                __builtin_amdgcn_global_load_lds(
                    (const unsigned int*)src_,
                    (unsigned int*)&sbuf[kn][w * 16 + j * 8][0], 16, 0, 0);
            }
        }

        // ---- prefetch next tile's indices under the stage latency ----
        int ofsB[2][Kn];
        LOADIDX(vt + 64, ofsB)       // clamped internally; wasted on last iter

        __syncthreads();   // vmcnt(0)+barrier: every wave's stages landed

        // ---- compute: 56 ds_read_b128 + 56 MFMA, no waits in between ----
        f32x4 acc[4];
#pragma unroll
        for (int t = 0; t < 4; ++t)
            acc[t] = (f32x4){0.f, 0.f, 0.f, 0.f};

        __builtin_amdgcn_s_setprio(1);
#pragma unroll
        for (int kn = 0; kn < Kn; ++kn) {
#pragma unroll
            for (int h = 0; h < 2; ++h) {
                const int q = h * 4 + quad;
#pragma unroll
                for (int t = 0; t < 4; ++t) {
                    const int r    = t * 16 + col;
                    const int slot = q ^ (r & 7);
                    const bf16x8 bf = *(const bf16x8*)&sbuf[kn][r][slot * 8];
                    acc[t] = __builtin_amdgcn_mfma_f32_16x16x32_bf16(
                        aW[kn * 2 + h], bf, acc[t], 0, 0, 0);
                }
            }
        }
        __builtin_amdgcn_s_setprio(0);

        // ---- epilogue: col = lane&15 -> vertex, row = quad*4+r -> o ----
        const int v0 = vt * 64;
#pragma unroll
        for (int r4 = 0; r4 < 4; ++r4) {
            const int o = w * 16 + quad * 4 + r4;
#pragma unroll
            for (int t = 0; t < 4; ++t) {
                const int n = v0 + t * 16 + col;
                if (n < Nn)
                    out[((size_t)bl * OUTn + o) * Nn + n] = acc[t][r4] + bv[r4];
            }
        }

#pragma unroll
        for (int j = 0; j < 2; ++j)
#pragma unroll
            for (int kn = 0; kn < Kn; ++kn)
                ofsA[j][kn] = ofsB[j][kn];
    }
#undef LOADIDX
}

// ---------------------------------------------------------------------------
// Fallback: no workspace needed. Pure f32. Slow but correct.
// ---------------------------------------------------------------------------
__global__ __launch_bounds__(256) void naive_kernel(
    const float* __restrict__ x, const int* __restrict__ nbr,
    const float* __restrict__ W, const float* __restrict__ bias,
    float* __restrict__ out)
{
    __shared__ float xs[4][Kn * Cn];
    const int v = threadIdx.x >> 6;
    const int o = threadIdx.x & 63;
    const int b = blockIdx.y;
    const int n = blockIdx.x * 4 + v;
    const bool ok = n < Nn;
    const int nn = ok ? n : 0;

#pragma unroll
    for (int k = 0; k < Kn; ++k) {
        int id = nbr[nn * Kn + k];
        id = id < 0 ? 0 : (id >= Nn ? Nn - 1 : id);
        xs[v][k * Cn + o] = x[((size_t)b * Cn + o) * Nn + id];
    }
    __syncthreads();

    float acc = bias[o];
    for (int j = 0; j < Kn * Cn; ++j)
        acc += W[o * (Kn * Cn) + j] * xs[v][j];

    if (ok)
        out[((size_t)b * OUTn + o) * Nn + n] = acc;
}

extern "C" void kernel_launch(void* const* d_in, const int* in_sizes, int n_in,
                              void* d_out, int out_size, void* d_ws, size_t ws_size,
                              hipStream_t stream)
{
    const float* x    = (const float*)d_in[0];
    const int*   nbr  = (const int*)d_in[1];
    const float* W    = (const float*)d_in[2];
    const float* bias = (const float*)d_in[3];
    float*       out  = (float*)d_out;

    const size_t w_bytes     = (size_t)OUTn * Kn * Cn * sizeof(__bf16); // 57344
    const size_t batch_bytes = (size_t)Nn * Cn * sizeof(__bf16);        // 5.24 MB
    int nb = 0;
    if (ws_size > w_bytes)
        nb = (int)((ws_size - w_bytes) / batch_bytes);
    if (nb > Bn) nb = Bn;

    if (nb >= Bn) {
        __bf16* Wb = (__bf16*)d_ws;
        __bf16* xT = (__bf16*)((char*)d_ws + w_bytes);

        dim3 tgrid((Nn + 127) / 128, Bn);
        transpose_kernel<<<tgrid, 256, 0, stream>>>(x, xT, W, Wb, 0);
        gconv_kernel<<<512, 256, 0, stream>>>(xT, nbr, Wb, bias, out);
    } else {
        dim3 ngrid((Nn + 3) / 4, Bn);
        naive_kernel<<<ngrid, 256, 0, stream>>>(x, nbr, W, bias, out);
    }
}

// Round 5
// 202.180 us; speedup vs baseline: 1.3094x; 1.0185x over previous
//
#include <hip/hip_runtime.h>
#include <hip/hip_bf16.h>

#define Bn   8
#define Cn   64
#define Nn   40962
#define Kn   7
#define OUTn 64
#define NVT  641      // 64-vertex tiles per batch
// flattened K dim = Kn*Cn = 448 = 14 chunks of 32

typedef __bf16 bf16x8 __attribute__((ext_vector_type(8)));
typedef __bf16 bf16x4 __attribute__((ext_vector_type(4)));
typedef float  f32x4  __attribute__((ext_vector_type(4)));

// ---------------------------------------------------------------------------
// Pass 1: transpose+convert x [B, C, N] f32 -> xT [B, N, C] bf16.
// (held constant -- measured ~33 us vs 20 us traffic floor)
// ---------------------------------------------------------------------------
__global__ __launch_bounds__(256) void transpose_kernel(
    const float* __restrict__ x, __bf16* __restrict__ xT,
    const float* __restrict__ W, __bf16* __restrict__ Wb, int b0)
{
    __shared__ unsigned int tile[64][65];   // [c][n-pair slot]; +1 pad
    const int tid  = threadIdx.x;
    const int lane = tid & 63;
    const int w    = tid >> 6;
    const int n0   = blockIdx.x * 128;
    const int bl   = blockIdx.y;
    const int b    = b0 + bl;
    const size_t xb = (size_t)b * Cn * Nn;

    // fused convw: first 112 blocks of bl==0 slice cover 28672 W elements
    if (bl == 0) {
        const int wi = blockIdx.x * 256 + tid;
        if (wi < OUTn * Kn * Cn) Wb[wi] = (__bf16)W[wi];
    }

    const int n = n0 + lane * 2;
    if (n < Nn) {
#pragma unroll
        for (int i = 0; i < 16; ++i) {
            const int c = w * 16 + i;
            const float2 v = *(const float2*)(x + xb + (size_t)c * Nn + n);
            const unsigned short ua =
                __builtin_bit_cast(unsigned short, (__bf16)v.x);
            const unsigned short ub =
                __builtin_bit_cast(unsigned short, (__bf16)v.y);
            tile[c][lane] = ((unsigned)ub << 16) | (unsigned)ua;
        }
    }
    __syncthreads();

    const int rsub = lane >> 3;
    const int cblk = lane & 7;
#pragma unroll
    for (int it = 0; it < 4; ++it) {
        const int row = it * 32 + w * 8 + rsub;
        const int n1  = n0 + row;
        if (n1 < Nn) {
            const int slot = row >> 1;
            const int sh   = (row & 1) * 16;
            bf16x8 frag;
#pragma unroll
            for (int e = 0; e < 8; ++e) {
                const unsigned u = tile[cblk * 8 + e][slot];
                frag[e] = __builtin_bit_cast(
                    __bf16, (unsigned short)((u >> sh) & 0xffffu));
            }
            *(bf16x8*)(xT + ((size_t)bl * Nn + n1) * Cn + cblk * 8) = frag;
        }
    }
}

// ---------------------------------------------------------------------------
// Pass 2 v6: persistent-block gather-GEMM, full-tile staging, 2x2 wave split.
// Round-4 post-mortem: at the o-split, every wave ds_read the ENTIRE 57 KB
// B-tile (56 b128/wave, 4x duplication across waves) -> LDS pipe was the
// largest per-CU term (448 b128 x 12 cy = 5376 cy/round, vs MFMA 2240 and
// L2 stage 2084). v6 splits waves 2x2: wave w = (wv=w&1, wo=w>>1) owns
// 32 vertices x 32 outputs; each bf ds_read is reused across the 2 output
// sub-strips -> 28 b128/wave, halving the LDS term to 2688 cy/round.
// Cost: aW doubles to 28 frags (112 VGPR) -- fine at 2 waves/SIMD.
// Everything else held: 512 persistent blocks (blk&7 = batch = XCD), aW
// loaded once per block, all-7-kn fire-and-forget staging, 2 barriers/tile,
// source-XOR'd chunks (slot depends only on col&7 -> mapping unchanged,
// proven conflict-free rounds 1-4).
// ---------------------------------------------------------------------------
__global__ __launch_bounds__(256, 2) void gconv_kernel(
    const __bf16* __restrict__ xT,    // [B, N, C] bf16
    const int*    __restrict__ nbr,   // [N*7] int32
    const __bf16* __restrict__ Wb,    // [64, 448] bf16
    const float*  __restrict__ bias,  // [64] f32
    float*        __restrict__ out)   // [B, 64, N] f32
{
    __shared__ __bf16 sbuf[Kn][64][64];   // 57344 B: [kn][vertex row][c]

    const int blk  = blockIdx.x;
    const int bl   = blk & 7;         // batch == XCD
    const int grp  = blk >> 3;        // 0..63 within batch
    const int w    = threadIdx.x >> 6;
    const int l    = threadIdx.x & 63;
    const int col  = l & 15;
    const int quad = l >> 4;
    const int rme  = l >> 3;
    const int srcoff = ((l & 7) ^ rme) * 16;
    const int wv   = w & 1;           // vertex half: t in {2wv, 2wv+1}
    const int wo   = w >> 1;          // output half: s in {2wo, 2wo+1}
    const __bf16* xb = xT + (size_t)bl * Nn * Cn;

    // ---- A fragments: W rows (2wo+s')*16+col, all 14 k-chunks, once ----
    bf16x8 aW[2][14];
#pragma unroll
    for (int s = 0; s < 2; ++s)
#pragma unroll
        for (int kc = 0; kc < 14; ++kc)
            aW[s][kc] = *(const bf16x8*)(Wb
                + (size_t)((wo * 2 + s) * 16 + col) * (Kn * Cn)
                + kc * 32 + quad * 8);

    float bv[2][4];
#pragma unroll
    for (int s = 0; s < 2; ++s)
#pragma unroll
        for (int r4 = 0; r4 < 4; ++r4)
            bv[s][r4] = bias[(wo * 2 + s) * 16 + quad * 4 + r4];

    // neighbor byte-offsets for the rows this lane stages (rows w*16+j*8+rme)
#define LOADIDX(vt_, dst_)                                                    \
    {                                                                         \
        _Pragma("unroll")                                                     \
        for (int j = 0; j < 2; ++j) {                                         \
            int v = (vt_)*64 + w * 16 + j * 8 + rme;                          \
            if (v > Nn - 1) v = Nn - 1;                                       \
            _Pragma("unroll")                                                 \
            for (int kn = 0; kn < Kn; ++kn) {                                 \
                int id = nbr[v * 7 + kn];                                     \
                id = id < 0 ? 0 : (id >= Nn ? Nn - 1 : id);                   \
                dst_[j][kn] = id * (Cn * 2);                                  \
            }                                                                 \
        }                                                                     \
    }

    int ofsA[2][Kn];
    LOADIDX(grp, ofsA)

    for (int vt = grp; vt < NVT; vt += 64) {
        __syncthreads();   // WAR: prev tile's laggard ds_reads done before restage

        // ---- stage ALL 7 kn (14 fire-and-forget global_load_lds / wave) ----
#pragma unroll
        for (int kn = 0; kn < Kn; ++kn) {
#pragma unroll
            for (int j = 0; j < 2; ++j) {
                const char* src_ = (const char*)xb + ofsA[j][kn] + srcoff;
                __builtin_amdgcn_global_load_lds(
                    (const unsigned int*)src_,
                    (unsigned int*)&sbuf[kn][w * 16 + j * 8][0], 16, 0, 0);
            }
        }

        // ---- prefetch next tile's indices under the stage latency ----
        int ofsB[2][Kn];
        LOADIDX(vt + 64, ofsB)       // clamped internally; wasted on last iter

        __syncthreads();   // vmcnt(0)+barrier: every wave's stages landed

        // ---- compute: 28 ds_read_b128 + 56 MFMA per wave ----
        f32x4 acc[2][2];
#pragma unroll
        for (int s = 0; s < 2; ++s)
#pragma unroll
            for (int t = 0; t < 2; ++t)
                acc[s][t] = (f32x4){0.f, 0.f, 0.f, 0.f};

        __builtin_amdgcn_s_setprio(1);
#pragma unroll
        for (int kn = 0; kn < Kn; ++kn) {
#pragma unroll
            for (int h = 0; h < 2; ++h) {
                const int q = h * 4 + quad;
#pragma unroll
                for (int t = 0; t < 2; ++t) {
                    const int r    = (wv * 2 + t) * 16 + col;
                    const int slot = q ^ (r & 7);
                    const bf16x8 bf = *(const bf16x8*)&sbuf[kn][r][slot * 8];
#pragma unroll
                    for (int s = 0; s < 2; ++s)
                        acc[s][t] = __builtin_amdgcn_mfma_f32_16x16x32_bf16(
                            aW[s][kn * 2 + h], bf, acc[s][t], 0, 0, 0);
                }
            }
        }
        __builtin_amdgcn_s_setprio(0);

        // ---- epilogue: col = lane&15 -> vertex, row = quad*4+r -> o ----
        const int v0 = vt * 64;
#pragma unroll
        for (int s = 0; s < 2; ++s) {
#pragma unroll
            for (int r4 = 0; r4 < 4; ++r4) {
                const int o = (wo * 2 + s) * 16 + quad * 4 + r4;
#pragma unroll
                for (int t = 0; t < 2; ++t) {
                    const int n = v0 + (wv * 2 + t) * 16 + col;
                    if (n < Nn)
                        out[((size_t)bl * OUTn + o) * Nn + n] =
                            acc[s][t][r4] + bv[s][r4];
                }
            }
        }

#pragma unroll
        for (int j = 0; j < 2; ++j)
#pragma unroll
            for (int kn = 0; kn < Kn; ++kn)
                ofsA[j][kn] = ofsB[j][kn];
    }
#undef LOADIDX
}

// ---------------------------------------------------------------------------
// Fallback: no workspace needed. Pure f32. Slow but correct.
// ---------------------------------------------------------------------------
__global__ __launch_bounds__(256) void naive_kernel(
    const float* __restrict__ x, const int* __restrict__ nbr,
    const float* __restrict__ W, const float* __restrict__ bias,
    float* __restrict__ out)
{
    __shared__ float xs[4][Kn * Cn];
    const int v = threadIdx.x >> 6;
    const int o = threadIdx.x & 63;
    const int b = blockIdx.y;
    const int n = blockIdx.x * 4 + v;
    const bool ok = n < Nn;
    const int nn = ok ? n : 0;

#pragma unroll
    for (int k = 0; k < Kn; ++k) {
        int id = nbr[nn * Kn + k];
        id = id < 0 ? 0 : (id >= Nn ? Nn - 1 : id);
        xs[v][k * Cn + o] = x[((size_t)b * Cn + o) * Nn + id];
    }
    __syncthreads();

    float acc = bias[o];
    for (int j = 0; j < Kn * Cn; ++j)
        acc += W[o * (Kn * Cn) + j] * xs[v][j];

    if (ok)
        out[((size_t)b * OUTn + o) * Nn + n] = acc;
}

extern "C" void kernel_launch(void* const* d_in, const int* in_sizes, int n_in,
                              void* d_out, int out_size, void* d_ws, size_t ws_size,
                              hipStream_t stream)
{
    const float* x    = (const float*)d_in[0];
    const int*   nbr  = (const int*)d_in[1];
    const float* W    = (const float*)d_in[2];
    const float* bias = (const float*)d_in[3];
    float*       out  = (float*)d_out;

    const size_t w_bytes     = (size_t)OUTn * Kn * Cn * sizeof(__bf16); // 57344
    const size_t batch_bytes = (size_t)Nn * Cn * sizeof(__bf16);        // 5.24 MB
    int nb = 0;
    if (ws_size > w_bytes)
        nb = (int)((ws_size - w_bytes) / batch_bytes);
    if (nb > Bn) nb = Bn;

    if (nb >= Bn) {
        __bf16* Wb = (__bf16*)d_ws;
        __bf16* xT = (__bf16*)((char*)d_ws + w_bytes);

        dim3 tgrid((Nn + 127) / 128, Bn);
        transpose_kernel<<<tgrid, 256, 0, stream>>>(x, xT, W, Wb, 0);
        gconv_kernel<<<512, 256, 0, stream>>>(xT, nbr, Wb, bias, out);
    } else {
        dim3 ngrid((Nn + 3) / 4, Bn);
        naive_kernel<<<ngrid, 256, 0, stream>>>(x, nbr, W, bias, out);
    }
}